// Round 3
// baseline (7268.624 us; speedup 1.0000x reference)
//
#include <hip/hip_runtime.h>

#define N_PTS 65536
#define DIM   1024
#define NCLS  256
#define NITER 25

typedef __attribute__((ext_vector_type(8)))  short short8;
typedef __attribute__((ext_vector_type(16))) float f32x16;

// ---- RNE float -> bf16 split helper ------------------------------------------
__device__ __forceinline__ unsigned short bf_split(float x, float& rem) {
    unsigned u = __float_as_uint(x);
    unsigned b = (u + 0x7fffu + ((u >> 16) & 1u)) & 0xffff0000u;
    rem = x - __uint_as_float(b);
    return (unsigned short)(b >> 16);
}
__device__ __forceinline__ unsigned short bf_rne(float x) {
    unsigned u = __float_as_uint(x);
    return (unsigned short)((u + 0x7fffu + ((u >> 16) & 1u)) >> 16);
}

// ---- async global->LDS 16B DMA (lds base must be wave-uniform) ---------------
__device__ __forceinline__ void gload_lds16(const void* g, void* l) {
    __builtin_amdgcn_global_load_lds(
        (const __attribute__((address_space(1))) unsigned int*)g,
        (__attribute__((address_space(3))) unsigned int*)l, 16, 0, 0);
}

// ---------------- argmax(logits) -> init labels (first-max tie-break) ---------
__global__ void k_argmax(const float* __restrict__ logits, int* __restrict__ labels) {
    int row  = blockIdx.x * 4 + (threadIdx.x >> 6);
    int lane = threadIdx.x & 63;
    float4 v = reinterpret_cast<const float4*>(logits + (size_t)row * NCLS)[lane];
    float bv = v.x; int bi = lane * 4;
    if (v.y > bv) { bv = v.y; bi = lane * 4 + 1; }
    if (v.z > bv) { bv = v.z; bi = lane * 4 + 2; }
    if (v.w > bv) { bv = v.w; bi = lane * 4 + 3; }
    #pragma unroll
    for (int off = 32; off >= 1; off >>= 1) {
        float ov = __shfl_down(bv, off, 64);
        int   oi = __shfl_down(bi, off, 64);
        if (ov > bv || (ov == bv && oi < bi)) { bv = ov; bi = oi; }
    }
    if (lane == 0) labels[row] = bi;
}

// ---------------- label histogram (init only; steady-state fused in k_assign) --
__global__ void k_hist(const int* __restrict__ labels, int* __restrict__ counts) {
    __shared__ int h[NCLS];
    h[threadIdx.x] = 0;
    __syncthreads();
    for (int i = blockIdx.x * blockDim.x + threadIdx.x; i < N_PTS;
         i += gridDim.x * blockDim.x)
        atomicAdd(&h[labels[i]], 1);
    __syncthreads();
    int v = h[threadIdx.x];
    if (v) atomicAdd(&counts[threadIdx.x], v);
}

// ---------------- segment-sum accumulate (fixed-point, deterministic) ---------
// grid (32 dim-slices, 8 point-chunks of 8192), block 512, LDS 64 KB
__global__ __launch_bounds__(512) void k_accum(const float* __restrict__ feat,
                                               const int* __restrict__ labels,
                                               float* __restrict__ partials) {
    __shared__ unsigned long long s[NCLS * 32];
    int tid = threadIdx.x;
    for (int i = tid; i < NCLS * 32; i += 512) s[i] = 0ull;
    __syncthreads();
    int slice = blockIdx.x;
    int chunk = blockIdx.y;
    int w = tid >> 6, l = tid & 63;
    int sub = l >> 3;
    int dq  = l & 7;
    const size_t dbase = (size_t)slice * 32 + dq * 4;
    for (int step = 0; step < 128; ++step) {
        int p = chunk * 8192 + step * 64 + w * 8 + sub;
        int c = labels[p];
        float4 f = *reinterpret_cast<const float4*>(feat + (size_t)p * DIM + dbase);
        unsigned long long* dst = &s[c * 32 + dq * 4];
        atomicAdd(dst + 0, (unsigned long long)__double2ll_rn((double)f.x * 16777216.0));
        atomicAdd(dst + 1, (unsigned long long)__double2ll_rn((double)f.y * 16777216.0));
        atomicAdd(dst + 2, (unsigned long long)__double2ll_rn((double)f.z * 16777216.0));
        atomicAdd(dst + 3, (unsigned long long)__double2ll_rn((double)f.w * 16777216.0));
    }
    __syncthreads();
    float* out = partials + (size_t)chunk * NCLS * DIM;
    for (int i = tid; i < NCLS * 32; i += 512) {
        int c = i >> 5, d = i & 31;
        out[(size_t)c * DIM + slice * 32 + d] =
            (float)((double)(long long)s[i] * (1.0 / 16777216.0));
    }
}

// ---------------- fused finalize + norms + bf16x3 splitB ----------------------
// grid 256 (one block per class), block 256 (thread t owns dims 4t..4t+3).
// Per-thread mapping identical to the old k_finalize / k_norms -> bitwise-same.
__global__ void k_final(const float* __restrict__ partials,
                        const int* __restrict__ counts,
                        float* __restrict__ centroids,
                        float* __restrict__ norms,
                        unsigned short* __restrict__ Bs) {
    int c = blockIdx.x, t = threadIdx.x;
    size_t off = ((size_t)c * 256 + t) * 4;
    float4 sum = make_float4(0.f, 0.f, 0.f, 0.f);
    for (int ch = 0; ch < 8; ++ch) {
        float4 p = *reinterpret_cast<const float4*>(partials + (size_t)ch * NCLS * DIM + off);
        sum.x += p.x; sum.y += p.y; sum.z += p.z; sum.w += p.w;
    }
    int cnt = counts[c];
    float4 outv;
    if (cnt > 0) {
        float fc = (float)cnt;
        outv = make_float4(sum.x / fc, sum.y / fc, sum.z / fc, sum.w / fc);
    } else {
        outv = *reinterpret_cast<const float4*>(centroids + off);
    }
    *reinterpret_cast<float4*>(centroids + off) = outv;

    // ---- norms (verbatim old k_norms reduction; outv == centroids row)
    float s = outv.x * outv.x + outv.y * outv.y + outv.z * outv.z + outv.w * outv.w;
    __shared__ float red[4];
    #pragma unroll
    for (int o = 32; o >= 1; o >>= 1) s += __shfl_down(s, o, 64);
    if ((t & 63) == 0) red[t >> 6] = s;
    __syncthreads();
    if (t == 0) norms[c] = red[0] + red[1] + red[2] + red[3];

    // ---- bf16x3 split, MFMA-fragment-ordered (same values as old k_splitB)
    int k = t * 4;
    int kc = k >> 5, kh = (k >> 4) & 1, jg = (k >> 3) & 1, j0 = k & 7;  // j0 in {0,4}
    int nt = c >> 5, lane = (c & 31) + 32 * jg;
    float xv[4] = {outv.x, outv.y, outv.z, outv.w};
    unsigned short hv[4], mv[4], lv[4];
    #pragma unroll
    for (int e = 0; e < 4; ++e) {
        float r1, r2;
        hv[e] = bf_split(xv[e], r1);
        mv[e] = bf_split(r1, r2);
        lv[e] = bf_rne(r2);
    }
    #pragma unroll
    for (int p = 0; p < 3; ++p) {
        size_t base = ((((size_t)kc * 3 + p) * 8 + nt) * 2 + kh) * 512 + (size_t)lane * 8 + j0;
        const unsigned short* sp = (p == 0) ? hv : (p == 1) ? mv : lv;
        *reinterpret_cast<uint2*>(&Bs[base]) = *reinterpret_cast<const uint2*>(sp);
    }
}

// ---------------- assign: bf16x3 MFMA GEMM + fused argmin + fused hist --------
// block 256 (4 waves), tile M=128 x N=256 (all classes).
// Software-pipelined 3-phase-per-kc schedule (m201-style):
//   LDS ring: 3 x 16 segments x 1KB (48 KB). Phase q reads buf q, issues DMA
//   for buf (q+2)%3 (2 phases ahead). Counted vmcnt (never 0 in steady state),
//   raw s_barrier (no drain). A via inline-asm loads 1 phase ahead; split
//   hoisted into prior kc's q2 phase. Per-acc MFMA order (q->kh->p) preserved
//   exactly -> bitwise-identical to the drained-barrier version.
__global__ __launch_bounds__(256, 2) void k_assign(
        const float* __restrict__ feat, const unsigned short* __restrict__ Bs,
        const float* __restrict__ norms, int* __restrict__ counts,
        int* __restrict__ out_labels) {
    __shared__ __align__(16) unsigned short Bl[3 * 16 * 512];   // 48 KB ring
    __shared__ int h[NCLS];
    int tid = threadIdx.x, w = tid >> 6, l = tid & 63;
    int cn = l & 31, jg = l >> 5;
    int p0 = blockIdx.x * 128;
    h[tid] = 0;   // hist zero; barriers below order it before epilogue use

    f32x16 acc[8];
    #pragma unroll
    for (int t = 0; t < 8; ++t)
        #pragma unroll
        for (int i = 0; i < 16; ++i) acc[t][i] = 0.f;

    const float* arow = feat + (size_t)(p0 + w * 32 + cn) * DIM + jg * 8;

    union AF { short8 v; unsigned short u[8]; } af[2][3];
    float4 ga0, ga1, ga2, ga3;

    auto issue_b = [&](int kc_, int q_, int rb_) {
        #pragma unroll
        for (int i = 0; i < 4; ++i) {
            int s = w * 4 + i;                 // s = ntl*2 + kh
            const unsigned short* g = Bs +
                ((((size_t)kc_ * 3 + q_) * 8 + (s >> 1)) * 2 + (s & 1)) * 512 +
                (size_t)l * 8;
            gload_lds16(g, &Bl[(rb_ * 16 + s) * 512]);
        }
    };
    auto load_a = [&](int kc_) {
        const float* ab = arow + kc_ * 32;
        asm volatile("global_load_dwordx4 %0, %1, off"           : "=v"(ga0) : "v"(ab) : "memory");
        asm volatile("global_load_dwordx4 %0, %1, off offset:16" : "=v"(ga1) : "v"(ab) : "memory");
        asm volatile("global_load_dwordx4 %0, %1, off offset:64" : "=v"(ga2) : "v"(ab) : "memory");
        asm volatile("global_load_dwordx4 %0, %1, off offset:80" : "=v"(ga3) : "v"(ab) : "memory");
    };
    auto split_a = [&]() {
        float xs[16] = {ga0.x, ga0.y, ga0.z, ga0.w, ga1.x, ga1.y, ga1.z, ga1.w,
                        ga2.x, ga2.y, ga2.z, ga2.w, ga3.x, ga3.y, ga3.z, ga3.w};
        #pragma unroll
        for (int kh = 0; kh < 2; ++kh)
            #pragma unroll
            for (int j = 0; j < 8; ++j) {
                float r1, r2;
                af[kh][0].u[j] = bf_split(xs[kh * 8 + j], r1);
                af[kh][1].u[j] = bf_split(r1, r2);
                af[kh][2].u[j] = bf_rne(r2);
            }
    };
    auto mfma_phase = [&](int rb, int np) {
        #pragma unroll
        for (int kh = 0; kh < 2; ++kh) {
            short8 bf[8];
            #pragma unroll
            for (int ntl = 0; ntl < 8; ++ntl)
                bf[ntl] = *reinterpret_cast<const short8*>(
                    &Bl[(rb * 16 + ntl * 2 + kh) * 512 + l * 8]);
            #pragma unroll
            for (int p = 0; p < 3; ++p)
                if (p < np) {
                    #pragma unroll
                    for (int ntl = 0; ntl < 8; ++ntl)
                        acc[ntl] = __builtin_amdgcn_mfma_f32_32x32x16_bf16(
                            af[kh][p].v, bf[ntl], acc[ntl], 0, 0, 0);
                }
        }
    };

    // ---- prologue: B(0,q0)->buf0, A(0), B(0,q1)->buf1; wait B0+A0; split
    issue_b(0, 0, 0);
    load_a(0);
    issue_b(0, 1, 1);
    asm volatile("s_waitcnt vmcnt(4)" ::: "memory");
    __builtin_amdgcn_sched_barrier(0);
    split_a();

    for (int kc = 0; kc < 32; ++kc) {
        const bool lastk = (kc == 31);
        // ---- phase q0 (reads buf0) : issue B(kc,q2)->buf2
        asm volatile("s_waitcnt vmcnt(4)" ::: "memory");
        __builtin_amdgcn_s_barrier();
        issue_b(kc, 2, 2);
        __builtin_amdgcn_s_setprio(1);
        mfma_phase(0, 3);
        __builtin_amdgcn_s_setprio(0);
        // ---- phase q1 (reads buf1) : issue B(kc+1,q0)->buf0, load A(kc+1)
        asm volatile("s_waitcnt vmcnt(4)" ::: "memory");
        __builtin_amdgcn_s_barrier();
        if (!lastk) {
            issue_b(kc + 1, 0, 0);
            load_a(kc + 1);
        }
        __builtin_amdgcn_s_setprio(1);
        mfma_phase(1, 2);
        __builtin_amdgcn_s_setprio(0);
        // ---- phase q2 (reads buf2) : issue B(kc+1,q1)->buf1; split A(kc+1)
        if (!lastk) { asm volatile("s_waitcnt vmcnt(8)" ::: "memory"); }
        else        { asm volatile("s_waitcnt vmcnt(0)" ::: "memory"); }
        __builtin_amdgcn_s_barrier();
        if (!lastk) {
            issue_b(kc + 1, 1, 1);
            asm volatile("s_waitcnt vmcnt(4)" ::: "memory");   // A(kc+1) landed
            __builtin_amdgcn_sched_barrier(0);
        }
        __builtin_amdgcn_s_setprio(1);
        mfma_phase(2, 1);
        __builtin_amdgcn_s_setprio(0);
        if (!lastk) split_a();
    }

    // epilogue: scores = ||mu||^2 - 2*dot ; argmin with first-index tie-break
    float nrm[8];
    #pragma unroll
    for (int ntl = 0; ntl < 8; ++ntl) nrm[ntl] = norms[ntl * 32 + cn];
    #pragma unroll
    for (int r = 0; r < 16; ++r) {
        unsigned long long key = ~0ull;
        #pragma unroll
        for (int ntl = 0; ntl < 8; ++ntl) {
            float s = nrm[ntl] - 2.0f * acc[ntl][r];
            unsigned u = __float_as_uint(s);
            u = (u & 0x80000000u) ? ~u : (u | 0x80000000u);
            unsigned long long kk =
                ((unsigned long long)u << 32) | (unsigned)(ntl * 32 + cn);
            key = (kk < key) ? kk : key;
        }
        #pragma unroll
        for (int off = 16; off >= 1; off >>= 1) {
            unsigned long long ok = __shfl_xor(key, off, 64);
            key = (ok < key) ? ok : key;
        }
        if (cn == 0) {
            int m = p0 + w * 32 + (r & 3) + 8 * (r >> 2) + 4 * jg;
            int lab = (int)(key & 0xffffffffull);
            out_labels[m] = lab;
            atomicAdd(&h[lab], 1);
        }
    }
    __syncthreads();
    int v = h[tid];
    if (v) atomicAdd(&counts[tid], v);
}

// ---------------- driver -------------------------------------------------------
extern "C" void kernel_launch(void* const* d_in, const int* in_sizes, int n_in,
                              void* d_out, int out_size, void* d_ws, size_t ws_size,
                              hipStream_t stream) {
    const float* feat   = (const float*)d_in[0];
    const float* logits = (const float*)d_in[1];
    int* out_labels = (int*)d_out;

    char* ws = (char*)d_ws;
    float* centroids            = (float*)ws;                        // 1 MB
    float* partials             = (float*)(ws + 0x100000);           // 8 MB
    float* norms                = (float*)(ws + 0x900000);           // 1 KB
    int*   counts               = (int*)  (ws + 0x901000);           // 1 KB
    int*   labels               = (int*)  (ws + 0x902000);           // 256 KB
    unsigned short* Bs          = (unsigned short*)(ws + 0x950000);  // 1.5 MB

    // ---- init: labels from argmax(logits); centroids from label centers
    k_argmax<<<N_PTS / 4, 256, 0, stream>>>(logits, labels);
    hipMemsetAsync(centroids, 0, (size_t)NCLS * DIM * sizeof(float), stream);
    hipMemsetAsync(counts, 0, NCLS * sizeof(int), stream);
    k_hist<<<64, 256, 0, stream>>>(labels, counts);
    k_accum<<<dim3(32, 8), 512, 0, stream>>>(feat, labels, partials);
    k_final<<<NCLS, 256, 0, stream>>>(partials, counts, centroids, norms, Bs);

    // ---- 25 Lloyd iterations (assign fuses hist; k_final fuses norms+splitB)
    for (int it = 0; it < NITER; ++it) {
        hipMemsetAsync(counts, 0, NCLS * sizeof(int), stream);
        k_assign<<<N_PTS / 128, 256, 0, stream>>>(feat, Bs, norms, counts, labels);
        k_accum<<<dim3(32, 8), 512, 0, stream>>>(feat, labels, partials);
        k_final<<<NCLS, 256, 0, stream>>>(partials, counts, centroids, norms, Bs);
    }

    // ---- final assignment -> output labels (counts write is harmless garbage)
    k_assign<<<N_PTS / 128, 256, 0, stream>>>(feat, Bs, norms, counts, out_labels);
}